// Round 5
// baseline (132.467 us; speedup 1.0000x reference)
//
#include <hip/hip_runtime.h>

#define NATOMS 8192
#define DD 128     // embedding dim
#define HH 256     // hidden dim
#define TI 4       // atoms per block in aggregation
#define MAXE 128   // max edges per atom (mean ~20)
#define MB 16      // nodes per block in MLP

// out is poisoned 0xAA before every launch; zero it for the atomic reduction.
__global__ void k_zero(float* out) { if (threadIdx.x == 0) out[0] = 0.0f; }

// ---- R1-PROVEN k_agg (verbatim): O(N^2) sweep, LDS edge lists, aggregate --
__global__ __launch_bounds__(256) void k_agg(const float* __restrict__ pos,
                                             const int* __restrict__ types,
                                             const float* __restrict__ emb,
                                             float* __restrict__ agg) {
  __shared__ float sw[TI][MAXE];
  __shared__ int   srow[TI][MAXE];
  __shared__ int   scnt[TI];
  const int tid = threadIdx.x;
  const int i0 = blockIdx.x * TI;
  if (tid < TI) scnt[tid] = 0;

  float pix[TI], piy[TI], piz[TI];
#pragma unroll
  for (int m = 0; m < TI; ++m) {   // uniform addresses -> scalar loads
    pix[m] = 10.0f * pos[(i0 + m) * 3 + 0];
    piy[m] = 10.0f * pos[(i0 + m) * 3 + 1];
    piz[m] = 10.0f * pos[(i0 + m) * 3 + 2];
  }
  __syncthreads();

  for (int j = tid; j < NATOMS; j += 256) {
    float pjx = 10.0f * pos[j * 3 + 0];
    float pjy = 10.0f * pos[j * 3 + 1];
    float pjz = 10.0f * pos[j * 3 + 2];
#pragma unroll
    for (int m = 0; m < TI; ++m) {
      float dx = pix[m] - pjx, dy = piy[m] - pjy, dz = piz[m] - pjz;
      float d2 = dx * dx;
      d2 = fmaf(dy, dy, d2);
      d2 = fmaf(dz, dz, d2);
      // ref mask: d2 > 1e-12 && sqrt(d2) <= 5  <=>  1e-12 < d2 <= 25
      if (d2 > 1e-12f && d2 <= 25.0f) {
        float w = __expf(-sqrtf(d2));
        int e = atomicAdd(&scnt[m], 1);
        if (e < MAXE) {
          sw[m][e] = w;
          srow[m][e] = types[j] * DD;
        }
      }
    }
  }
  __syncthreads();

  // 256 threads = 2 groups of 128 dims; group g handles atoms {g, g+2}
  const int d = tid & (DD - 1);
  const int g = tid >> 7;
#pragma unroll
  for (int mm = 0; mm < TI; mm += 2) {
    int m = g + mm;
    int nc = min(scnt[m], MAXE);
    float a = 0.0f;
    for (int e = 0; e < nc; ++e)
      a = fmaf(sw[m][e], emb[srow[m][e] + d], a);
    agg[(size_t)(i0 + m) * DD + d] = a;
  }
}

// ---- MLP, hidden-split: block (bx,by) does hidden half by*128 for 16 nodes.
// e_node = sum_h relu(z_h) w2_h is separable in h -> halves sum via atomics.
// Minimal diff from the R1-proven kernel: acc1/w1 dropped, hb offset added.
__global__ __launch_bounds__(256) void k_mlp(const int* __restrict__ types,
                                             const float* __restrict__ emb,
                                             const float* __restrict__ agg,
                                             const float* __restrict__ W1,
                                             const float* __restrict__ w2,
                                             float* __restrict__ out) {
  __shared__ float sf[2 * DD][MB];  // feat transposed [j][m], 16 KB
  __shared__ float sred[4];
  const int tid = threadIdx.x;
  const int n0 = blockIdx.x * MB;
  const int hb = blockIdx.y << 7;   // hidden-half offset: 0 or 128

  for (int idx = tid; idx < MB * 2 * DD; idx += 256) {
    int j = idx >> 4;        // 0..255
    int m = idx & (MB - 1);  // 0..15
    float v;
    if (j < DD) v = emb[types[n0 + m] * DD + j];
    else        v = agg[(size_t)(n0 + m) * DD + (j - DD)];
    sf[j][m] = v;
  }
  __syncthreads();

  const int tx = tid & 127;
  const int ty = tid >> 7;
  float acc0[8];
#pragma unroll
  for (int m = 0; m < 8; ++m) acc0[m] = 0.0f;

  const float* fbase = &sf[0][ty * 8];
#pragma unroll 4
  for (int j = 0; j < 2 * DD; ++j) {
    float w0 = W1[j * HH + hb + tx];     // coalesced, L2-hot (shared across bx)
    float f[8];
    *(float4*)&f[0] = *(const float4*)(fbase + j * MB);      // LDS broadcast
    *(float4*)&f[4] = *(const float4*)(fbase + j * MB + 4);
#pragma unroll
    for (int m = 0; m < 8; ++m)
      acc0[m] = fmaf(f[m], w0, acc0[m]);
  }

  float s0 = 0.0f;
#pragma unroll
  for (int m = 0; m < 8; ++m)
    s0 += fmaxf(acc0[m], 0.0f);
  float p = s0 * w2[hb + tx];
#pragma unroll
  for (int off = 32; off; off >>= 1) p += __shfl_down(p, off);  // wave64 reduce
  if ((tid & 63) == 0) sred[tid >> 6] = p;
  __syncthreads();
  if (tid == 0)
    atomicAdd(out, (sred[0] + sred[1] + sred[2] + sred[3]) * 0.2390057361376673f);
}

extern "C" void kernel_launch(void* const* d_in, const int* in_sizes, int n_in,
                              void* d_out, int out_size, void* d_ws, size_t ws_size,
                              hipStream_t stream) {
  const float* pos = (const float*)d_in[0];
  const int*   typ = (const int*)d_in[1];
  const float* emb = (const float*)d_in[2];
  const float* W1  = (const float*)d_in[3];
  const float* w2  = (const float*)d_in[4];
  float* out = (float*)d_out;
  float* agg = (float*)d_ws;  // 8192*128 floats = 4 MB scratch

  hipLaunchKernelGGL(k_zero, dim3(1), dim3(64), 0, stream, out);
  hipLaunchKernelGGL(k_agg, dim3(NATOMS / TI), dim3(256), 0, stream,
                     pos, typ, emb, agg);
  hipLaunchKernelGGL(k_mlp, dim3(NATOMS / MB, 2), dim3(256), 0, stream,
                     typ, emb, agg, W1, w2, out);
}

// Round 6
// 124.356 us; speedup vs baseline: 1.0652x; 1.0652x over previous
//
#include <hip/hip_runtime.h>

#define NATOMS 8192
#define DD 128     // embedding dim
#define HH 256     // hidden dim
#define TI 4       // atoms per block in aggregation
#define MAXE 128   // max edges per atom (mean ~20)
#define MB 16      // nodes per block in MLP

// out is poisoned 0xAA before every launch; zero it for the atomic reduction.
__global__ void k_zero(float* out) { if (threadIdx.x == 0) out[0] = 0.0f; }

// ---- R1-PROVEN k_agg (verbatim): O(N^2) sweep, LDS edge lists, aggregate --
__global__ __launch_bounds__(256) void k_agg(const float* __restrict__ pos,
                                             const int* __restrict__ types,
                                             const float* __restrict__ emb,
                                             float* __restrict__ agg) {
  __shared__ float sw[TI][MAXE];
  __shared__ int   srow[TI][MAXE];
  __shared__ int   scnt[TI];
  const int tid = threadIdx.x;
  const int i0 = blockIdx.x * TI;
  if (tid < TI) scnt[tid] = 0;

  float pix[TI], piy[TI], piz[TI];
#pragma unroll
  for (int m = 0; m < TI; ++m) {   // uniform addresses -> scalar loads
    pix[m] = 10.0f * pos[(i0 + m) * 3 + 0];
    piy[m] = 10.0f * pos[(i0 + m) * 3 + 1];
    piz[m] = 10.0f * pos[(i0 + m) * 3 + 2];
  }
  __syncthreads();

  for (int j = tid; j < NATOMS; j += 256) {
    float pjx = 10.0f * pos[j * 3 + 0];
    float pjy = 10.0f * pos[j * 3 + 1];
    float pjz = 10.0f * pos[j * 3 + 2];
#pragma unroll
    for (int m = 0; m < TI; ++m) {
      float dx = pix[m] - pjx, dy = piy[m] - pjy, dz = piz[m] - pjz;
      float d2 = dx * dx;
      d2 = fmaf(dy, dy, d2);
      d2 = fmaf(dz, dz, d2);
      // ref mask: d2 > 1e-12 && sqrt(d2) <= 5  <=>  1e-12 < d2 <= 25
      if (d2 > 1e-12f && d2 <= 25.0f) {
        float w = __expf(-sqrtf(d2));
        int e = atomicAdd(&scnt[m], 1);
        if (e < MAXE) {
          sw[m][e] = w;
          srow[m][e] = types[j] * DD;
        }
      }
    }
  }
  __syncthreads();

  // 256 threads = 2 groups of 128 dims; group g handles atoms {g, g+2}
  const int d = tid & (DD - 1);
  const int g = tid >> 7;
#pragma unroll
  for (int mm = 0; mm < TI; mm += 2) {
    int m = g + mm;
    int nc = min(scnt[m], MAXE);
    float a = 0.0f;
    for (int e = 0; e < nc; ++e)
      a = fmaf(sw[m][e], emb[srow[m][e] + d], a);
    agg[(size_t)(i0 + m) * DD + d] = a;
  }
}

// ---- MLP with 2-D register tile: thread (tx=tid&63, ty=tid>>6) computes
// hidden {tx+64k, k<4} x nodes {ty*4+m, m<4} -> 16 acc. Per j: ONE b128 LDS
// broadcast (wave-uniform addr) + 4 coalesced W1 loads -> 16 FMA. 4x fewer
// LDS-pipe cycles than R5 (which was LDS-issue bound at ~41 us).
__global__ __launch_bounds__(256) void k_mlp(const int* __restrict__ types,
                                             const float* __restrict__ emb,
                                             const float* __restrict__ agg,
                                             const float* __restrict__ W1,
                                             const float* __restrict__ w2,
                                             float* __restrict__ out) {
  __shared__ float sf[2 * DD][MB];  // feat transposed [j][m], 16 KB
  __shared__ float sred[4];
  const int tid = threadIdx.x;
  const int n0 = blockIdx.x * MB;

  // staging: verbatim R1 (proven)
  for (int idx = tid; idx < MB * 2 * DD; idx += 256) {
    int j = idx >> 4;        // 0..255
    int m = idx & (MB - 1);  // 0..15
    float v;
    if (j < DD) v = emb[types[n0 + m] * DD + j];
    else        v = agg[(size_t)(n0 + m) * DD + (j - DD)];
    sf[j][m] = v;
  }
  __syncthreads();

  const int tx = tid & 63;
  const int ty = tid >> 6;           // 0..3 -> node group ty*4 (wave-uniform)
  float acc[4][4];                   // [k: h=tx+64k][m: node ty*4+m]
#pragma unroll
  for (int k = 0; k < 4; ++k)
#pragma unroll
    for (int m = 0; m < 4; ++m) acc[k][m] = 0.0f;

  const float* fbase = &sf[0][ty * 4];
  const float* wbase = W1 + tx;
#pragma unroll 4
  for (int j = 0; j < 2 * DD; ++j) {
    float4 f = *(const float4*)(fbase + j * MB);   // wave-uniform broadcast
    float w[4];
#pragma unroll
    for (int k = 0; k < 4; ++k)
      w[k] = wbase[j * HH + 64 * k];               // coalesced across lanes
#pragma unroll
    for (int k = 0; k < 4; ++k)
#pragma unroll
      for (int m = 0; m < 4; ++m)
        acc[k][m] = fmaf(((const float*)&f)[m], w[k], acc[k][m]);
  }

  float p = 0.0f;
#pragma unroll
  for (int k = 0; k < 4; ++k) {
    float w2k = w2[tx + 64 * k];
    float s = 0.0f;
#pragma unroll
    for (int m = 0; m < 4; ++m) s += fmaxf(acc[k][m], 0.0f);
    p = fmaf(s, w2k, p);
  }
#pragma unroll
  for (int off = 32; off; off >>= 1) p += __shfl_down(p, off);  // wave64 reduce
  if ((tid & 63) == 0) sred[ty] = p;   // lane 0 of each wave
  __syncthreads();
  if (tid == 0)
    atomicAdd(out, (sred[0] + sred[1] + sred[2] + sred[3]) * 0.2390057361376673f);
}

extern "C" void kernel_launch(void* const* d_in, const int* in_sizes, int n_in,
                              void* d_out, int out_size, void* d_ws, size_t ws_size,
                              hipStream_t stream) {
  const float* pos = (const float*)d_in[0];
  const int*   typ = (const int*)d_in[1];
  const float* emb = (const float*)d_in[2];
  const float* W1  = (const float*)d_in[3];
  const float* w2  = (const float*)d_in[4];
  float* out = (float*)d_out;
  float* agg = (float*)d_ws;  // 8192*128 floats = 4 MB scratch

  hipLaunchKernelGGL(k_zero, dim3(1), dim3(64), 0, stream, out);
  hipLaunchKernelGGL(k_agg, dim3(NATOMS / TI), dim3(256), 0, stream,
                     pos, typ, emb, agg);
  hipLaunchKernelGGL(k_mlp, dim3(NATOMS / MB), dim3(256), 0, stream,
                     typ, emb, agg, W1, w2, out);
}